// Round 5
// baseline (3907.858 us; speedup 1.0000x reference)
//
#include <hip/hip_runtime.h>
#include <hip/hip_bf16.h>

#define T_TOK 4096
#define HID   2048
#define FFN   7168
#define NEXP  8
#define BM    128
#define BN    128
#define MT    16
#define NPAIR (T_TOK * 2)
#define KT1   (HID / 32)   // 64 k-slabs for GEMM1
#define SLAB  8192         // bytes per [128n][32k] bf16 slab

typedef __attribute__((ext_vector_type(8))) short bf16x8;
typedef __attribute__((ext_vector_type(4))) short bf16x4;
typedef __attribute__((ext_vector_type(4))) float f32x4;

union F4 { float4 v; float f[4]; };

__device__ __forceinline__ short f2bfs(float f) {
    unsigned u = __float_as_uint(f);
    return (short)((u + 0x7FFFu + ((u >> 16) & 1u)) >> 16);
}
// slot swizzle for 64B rows (4x 16B slots): slot holding k-group g of row n is g ^ swzi(n)
__device__ __forceinline__ int swzi(int n) { return (n ^ (n >> 2)) & 3; }

__device__ __forceinline__ void gl16(const void* g, void* l) {
    __builtin_amdgcn_global_load_lds(
        (const __attribute__((address_space(1))) unsigned int*)g,
        (__attribute__((address_space(3))) unsigned int*)l, 16, 0, 0);
}

// ---------------- Router ----------------
__global__ __launch_bounds__(256) void moe_router(
    const float* __restrict__ x, const float* __restrict__ gw,
    int* __restrict__ counts, int* __restrict__ sel0, int* __restrict__ sel1,
    float* __restrict__ w0o, float* __restrict__ w1o)
{
    int wave = threadIdx.x >> 6, lane = threadIdx.x & 63;
    int t = blockIdx.x * 4 + wave;
    const float* xr = x + (size_t)t * HID;
    float acc[NEXP];
#pragma unroll
    for (int e = 0; e < NEXP; ++e) acc[e] = 0.f;
    for (int i = 0; i < HID / 64; ++i) {
        int k = lane + i * 64;
        float xv = xr[k];
        const float4* g = reinterpret_cast<const float4*>(gw + (size_t)k * NEXP);
        float4 g0 = g[0], g1 = g[1];
        acc[0] += xv * g0.x; acc[1] += xv * g0.y; acc[2] += xv * g0.z; acc[3] += xv * g0.w;
        acc[4] += xv * g1.x; acc[5] += xv * g1.y; acc[6] += xv * g1.z; acc[7] += xv * g1.w;
    }
#pragma unroll
    for (int e = 0; e < NEXP; ++e) {
        float v = acc[e];
#pragma unroll
        for (int s = 32; s > 0; s >>= 1) v += __shfl_xor(v, s);
        acc[e] = v;
    }
    if (lane == 0) {
        float mx = acc[0];
        for (int e = 1; e < NEXP; ++e) mx = fmaxf(mx, acc[e]);
        float p[NEXP];
        for (int e = 0; e < NEXP; ++e) p[e] = __expf(acc[e] - mx);
        int e0 = 0;
        for (int e = 1; e < NEXP; ++e) if (p[e] > p[e0]) e0 = e;
        int e1 = (e0 == 0) ? 1 : 0;
        for (int e = 0; e < NEXP; ++e) if (e != e0 && p[e] > p[e1]) e1 = e;
        float rs = p[e0] + p[e1];
        sel0[t] = e0; sel1[t] = e1;
        w0o[t] = p[e0] / rs; w1o[t] = p[e1] / rs;
        atomicAdd(&counts[e0], 1); atomicAdd(&counts[e1], 1);
    }
}

__global__ void moe_bases(const int* __restrict__ counts, int* __restrict__ bases)
{
    if (threadIdx.x == 0 && blockIdx.x == 0) {
        int b = 0;
        for (int e = 0; e < NEXP; ++e) { bases[e] = b; b += counts[e]; }
    }
}

// ---------------- Deterministic scatter ----------------
__global__ __launch_bounds__(256) void moe_scatter(
    const int* __restrict__ sel0, const int* __restrict__ sel1,
    const float* __restrict__ w0, const float* __restrict__ w1,
    const int* __restrict__ bases, int* __restrict__ pairTok, float* __restrict__ pairW)
{
    int e = blockIdx.x;
    __shared__ int wsum[4];
    __shared__ int runningS;
    int tid = threadIdx.x, wave = tid >> 6, lane = tid & 63;
    if (tid == 0) runningS = bases[e];
    __syncthreads();
    for (int i0 = 0; i0 < T_TOK; i0 += 256) {
        int t = i0 + tid;
        bool f0 = (sel0[t] == e), f1 = (sel1[t] == e);
        bool sel = f0 || f1;
        unsigned long long mm = __ballot(sel);
        if (lane == 0) wsum[wave] = __popcll(mm);
        __syncthreads();
        int woff = 0;
#pragma unroll
        for (int w = 0; w < 4; ++w) if (w < wave) woff += wsum[w];
        int tot = wsum[0] + wsum[1] + wsum[2] + wsum[3];
        int pre = __popcll(mm & ((1ull << lane) - 1ull));
        if (sel) {
            int pos = runningS + woff + pre;
            pairTok[pos] = t;
            pairW[pos] = f0 ? w0[t] : w1[t];
        }
        __syncthreads();
        if (tid == 0) runningS += tot;
        __syncthreads();
    }
}

// ---------------- xperm: gather routed token rows as bf16 ----------------
__global__ __launch_bounds__(256) void moe_xperm(
    const float* __restrict__ x, const int* __restrict__ pairTok,
    short* __restrict__ xperm)
{
    int p = blockIdx.x * 4 + (threadIdx.x >> 6);
    int lane = threadIdx.x & 63;
    const float* s = x + (size_t)pairTok[p] * HID;
    short* d = xperm + (size_t)p * HID;
#pragma unroll
    for (int i = 0; i < HID / 512; ++i) {
        int k = (i * 64 + lane) * 8;
        float4 f0 = *reinterpret_cast<const float4*>(s + k);
        float4 f1 = *reinterpret_cast<const float4*>(s + k + 4);
        union { bf16x8 v; short sh[8]; } u;
        u.sh[0] = f2bfs(f0.x); u.sh[1] = f2bfs(f0.y); u.sh[2] = f2bfs(f0.z); u.sh[3] = f2bfs(f0.w);
        u.sh[4] = f2bfs(f1.x); u.sh[5] = f2bfs(f1.y); u.sh[6] = f2bfs(f1.z); u.sh[7] = f2bfs(f1.w);
        *reinterpret_cast<bf16x8*>(d + k) = u.v;
    }
}

// ---------------- retile: fp32 [K][N] -> bf16 swizzled 8KB slabs [n:128][k:32] ----------------
// slab L = (e*NB + nb)*KT + kt; byte(n,k) = n*64 + ((k>>3 ^ swzi(n))*16) + (k&7)*2
__global__ __launch_bounds__(256) void moe_retile(
    const float* __restrict__ src, size_t eStride, int rowStride,
    short* __restrict__ dst, int NB, int KT)
{
    int L = blockIdx.x;
    int e = L / (NB * KT);
    int r = L - e * (NB * KT);
    int nb = r / KT, kt = r - nb * KT;
    const float* s0 = src + (size_t)e * eStride + (size_t)(kt * 32) * rowStride + nb * 128;
    __shared__ __align__(16) short S[4096];
    int t = threadIdx.x;
    int kq = t >> 5, nq = t & 31;            // 4x4 unit at k=kq*4, n=nq*4
    const float* p = s0 + (size_t)(kq * 4) * rowStride + nq * 4;
    F4 r0, r1, r2, r3;
    r0.v = *reinterpret_cast<const float4*>(p);
    r1.v = *reinterpret_cast<const float4*>(p + rowStride);
    r2.v = *reinterpret_cast<const float4*>(p + 2 * (size_t)rowStride);
    r3.v = *reinterpret_cast<const float4*>(p + 3 * (size_t)rowStride);
#pragma unroll
    for (int c = 0; c < 4; ++c) {
        int n = nq * 4 + c;
        bf16x4 v = { f2bfs(r0.f[c]), f2bfs(r1.f[c]), f2bfs(r2.f[c]), f2bfs(r3.f[c]) };
        unsigned byte = (unsigned)(n * 64 + (((kq >> 1) ^ swzi(n)) * 16) + (kq & 1) * 8);
        *reinterpret_cast<bf16x4*>(reinterpret_cast<char*>(S) + byte) = v;
    }
    __syncthreads();
    char* d = reinterpret_cast<char*>(dst) + (size_t)L * SLAB;
    const char* sc = reinterpret_cast<const char*>(S);
    *reinterpret_cast<bf16x8*>(d + t * 16) = *reinterpret_cast<const bf16x8*>(sc + t * 16);
    *reinterpret_cast<bf16x8*>(d + t * 16 + 4096) = *reinterpret_cast<const bf16x8*>(sc + t * 16 + 4096);
}

// ---------------- GEMM1: h = silu(x@W1)*(x@W3), 2-phase dbuf pipeline ----------------
__global__ __launch_bounds__(256, 3) void moe_g1(
    const short* __restrict__ xperm, const short* __restrict__ w1r, const short* __restrict__ w3r,
    const int* __restrict__ counts, const int* __restrict__ bases,
    short* __restrict__ hbuf, int NBc, int Fc)
{
    int L = blockIdx.x;
    int e = L & 7;                        // expert <-> XCD binding
    int i = L >> 3;
    int nb = i / MT, m = i - nb * MT;
    int cnt = counts[e];
    int m0 = m * BM;
    if (m0 >= cnt) return;
    int base = bases[e];
    int rows = cnt - m0; if (rows > BM) rows = BM;

    __shared__ __align__(16) short As[2][4096], B1s[2][4096], B3s[2][4096];

    int tid = threadIdx.x, lane = tid & 63, w = tid >> 6;
    int wm = (w >> 1) * 64, wn = (w & 1) * 64;

    // A per-lane swizzle-baked sources (wave w stages rows [w*32, w*32+32))
    const char* aS[2];
#pragma unroll
    for (int j = 0; j < 2; ++j) {
        int row = w * 32 + j * 16 + (lane >> 2);
        aS[j] = reinterpret_cast<const char*>(xperm) +
                (size_t)(base + m0 + row) * (HID * 2) +
                (unsigned)(((lane & 3) ^ swzi(row)) * 16);
    }
    size_t slabBase = (size_t)((e * NBc + nb) * KT1) * SLAB;
    const char* b1S = reinterpret_cast<const char*>(w1r) + slabBase + w * 2048 + lane * 16;
    const char* b3S = reinterpret_cast<const char*>(w3r) + slabBase + w * 2048 + lane * 16;

    f32x4 acc1[4][4], acc3[4][4];
#pragma unroll
    for (int a = 0; a < 4; ++a)
#pragma unroll
        for (int b = 0; b < 4; ++b) { acc1[a][b] = (f32x4){0.f,0.f,0.f,0.f}; acc3[a][b] = (f32x4){0.f,0.f,0.f,0.f}; }

    // loop-invariant fragment read offsets (BK=32: one k-group per lane)
    unsigned aRB[4], bRB[4];
    int gq = lane >> 4;
#pragma unroll
    for (int a = 0; a < 4; ++a) {
        int rA = wm + a * 16 + (lane & 15);
        aRB[a] = (unsigned)(rA * 64 + ((gq ^ swzi(rA)) * 16));
        int rB = wn + a * 16 + (lane & 15);
        bRB[a] = (unsigned)(rB * 64 + ((gq ^ swzi(rB)) * 16));
    }

#define G1_STAGE(B, KT_IDX) do { \
    int _kt = (KT_IDX); \
    gl16(aS[0] + (size_t)_kt * 64, (char*)As[B] + w * 2048); \
    gl16(aS[1] + (size_t)_kt * 64, (char*)As[B] + w * 2048 + 1024); \
    gl16(b1S + (size_t)_kt * SLAB, (char*)B1s[B] + w * 2048); \
    gl16(b1S + (size_t)_kt * SLAB + 1024, (char*)B1s[B] + w * 2048 + 1024); \
    gl16(b3S + (size_t)_kt * SLAB, (char*)B3s[B] + w * 2048); \
    gl16(b3S + (size_t)_kt * SLAB + 1024, (char*)B3s[B] + w * 2048 + 1024); \
} while (0)

#define G1_COMPUTE(B) do { \
    bf16x8 af[4], b1f[4], b3f[4]; \
    _Pragma("unroll") \
    for (int a = 0; a < 4; ++a) \
        af[a] = *reinterpret_cast<const bf16x8*>((const char*)As[B] + aRB[a]); \
    _Pragma("unroll") \
    for (int b = 0; b < 4; ++b) { \
        b1f[b] = *reinterpret_cast<const bf16x8*>((const char*)B1s[B] + bRB[b]); \
        b3f[b] = *reinterpret_cast<const bf16x8*>((const char*)B3s[B] + bRB[b]); \
    } \
    _Pragma("unroll") \
    for (int a = 0; a < 4; ++a) \
        _Pragma("unroll") \
        for (int b = 0; b < 4; ++b) { \
            acc1[a][b] = __builtin_amdgcn_mfma_f32_16x16x32_bf16(af[a], b1f[b], acc1[a][b], 0, 0, 0); \
            acc3[a][b] = __builtin_amdgcn_mfma_f32_16x16x32_bf16(af[a], b3f[b], acc3[a][b], 0, 0, 0); \
        } \
} while (0)

    G1_STAGE(0, 0);
    __syncthreads();
#pragma unroll 1
    for (int kt = 0; kt < KT1; kt += 2) {
        G1_STAGE(1, kt + 1);       // issue next-tile loads BEFORE compute
        G1_COMPUTE(0);
        __syncthreads();           // drains buf1 staging, releases buf0
        if (kt + 2 < KT1) G1_STAGE(0, kt + 2);
        G1_COMPUTE(1);
        __syncthreads();
    }

    int hi = lane >> 4, lo = lane & 15;
#pragma unroll
    for (int a = 0; a < 4; ++a) {
#pragma unroll
        for (int q = 0; q < 4; ++q) {
            int rowL = wm + a * 16 + hi * 4 + q;
            if (rowL < rows) {
                short* dst = hbuf + (size_t)(base + m0 + rowL) * Fc + nb * 128;
#pragma unroll
                for (int b = 0; b < 4; ++b) {
                    float z = acc1[a][b][q];
                    float hv = (z / (1.f + __expf(-z))) * acc3[a][b][q];
                    dst[wn + b * 16 + lo] = f2bfs(hv);
                }
            }
        }
    }
}

// ---------------- GEMM2: out[tok] += w * (h @ W2), 2-phase dbuf ----------------
__global__ __launch_bounds__(256, 4) void moe_g2(
    const short* __restrict__ hbuf, const short* __restrict__ w2r,
    const int* __restrict__ counts, const int* __restrict__ bases,
    const int* __restrict__ pairTok, const float* __restrict__ pairW,
    float* __restrict__ out, int Fc, int KT2)
{
    const int NB2 = HID / BN;             // 16
    int L = blockIdx.x;
    int e = L & 7;
    int i = L >> 3;
    int nb = i / MT, m = i - nb * MT;
    int cnt = counts[e];
    int m0 = m * BM;
    if (m0 >= cnt) return;
    int base = bases[e];
    int rows = cnt - m0; if (rows > BM) rows = BM;

    __shared__ __align__(16) short As[2][4096], Bs[2][4096];
    __shared__ int tokS[BM];
    __shared__ float wS[BM];

    int tid = threadIdx.x, lane = tid & 63, w = tid >> 6;
    if (tid < BM) {
        tokS[tid] = (tid < rows) ? pairTok[base + m0 + tid] : 0;
        wS[tid]   = (tid < rows) ? pairW[base + m0 + tid] : 0.f;
    }
    int wm = (w >> 1) * 64, wn = (w & 1) * 64;

    const char* aS[2];
#pragma unroll
    for (int j = 0; j < 2; ++j) {
        int row = w * 32 + j * 16 + (lane >> 2);
        aS[j] = reinterpret_cast<const char*>(hbuf) +
                (size_t)(base + m0 + row) * (size_t)(Fc * 2) +
                (unsigned)(((lane & 3) ^ swzi(row)) * 16);
    }
    size_t slabBase = (size_t)((e * NB2 + nb) * KT2) * SLAB;
    const char* bS = reinterpret_cast<const char*>(w2r) + slabBase + w * 2048 + lane * 16;

    f32x4 acc[4][4];
#pragma unroll
    for (int a = 0; a < 4; ++a)
#pragma unroll
        for (int b = 0; b < 4; ++b) acc[a][b] = (f32x4){0.f,0.f,0.f,0.f};

    unsigned aRB[4], bRB[4];
    int gq = lane >> 4;
#pragma unroll
    for (int a = 0; a < 4; ++a) {
        int rA = wm + a * 16 + (lane & 15);
        aRB[a] = (unsigned)(rA * 64 + ((gq ^ swzi(rA)) * 16));
        int rB = wn + a * 16 + (lane & 15);
        bRB[a] = (unsigned)(rB * 64 + ((gq ^ swzi(rB)) * 16));
    }

#define G2_STAGE(B, KT_IDX) do { \
    int _kt = (KT_IDX); \
    gl16(aS[0] + (size_t)_kt * 64, (char*)As[B] + w * 2048); \
    gl16(aS[1] + (size_t)_kt * 64, (char*)As[B] + w * 2048 + 1024); \
    gl16(bS + (size_t)_kt * SLAB, (char*)Bs[B] + w * 2048); \
    gl16(bS + (size_t)_kt * SLAB + 1024, (char*)Bs[B] + w * 2048 + 1024); \
} while (0)

#define G2_COMPUTE(B) do { \
    bf16x8 af[4], bfr[4]; \
    _Pragma("unroll") \
    for (int a = 0; a < 4; ++a) \
        af[a] = *reinterpret_cast<const bf16x8*>((const char*)As[B] + aRB[a]); \
    _Pragma("unroll") \
    for (int b = 0; b < 4; ++b) \
        bfr[b] = *reinterpret_cast<const bf16x8*>((const char*)Bs[B] + bRB[b]); \
    _Pragma("unroll") \
    for (int a = 0; a < 4; ++a) \
        _Pragma("unroll") \
        for (int b = 0; b < 4; ++b) \
            acc[a][b] = __builtin_amdgcn_mfma_f32_16x16x32_bf16(af[a], bfr[b], acc[a][b], 0, 0, 0); \
} while (0)

    __syncthreads();                      // tokS/wS visible
    G2_STAGE(0, 0);
    __syncthreads();
#pragma unroll 1
    for (int kt = 0; kt < KT2; kt += 2) {
        G2_STAGE(1, kt + 1);
        G2_COMPUTE(0);
        __syncthreads();
        if (kt + 2 < KT2) G2_STAGE(0, kt + 2);
        G2_COMPUTE(1);
        __syncthreads();
    }

    int hi = lane >> 4, lo = lane & 15;
#pragma unroll
    for (int a = 0; a < 4; ++a) {
#pragma unroll
        for (int q = 0; q < 4; ++q) {
            int rowL = wm + a * 16 + hi * 4 + q;
            if (rowL < rows) {
                float wt = wS[rowL];
                float* dst = out + (size_t)tokS[rowL] * HID + nb * 128;
#pragma unroll
                for (int b = 0; b < 4; ++b)
                    atomicAdd(dst + wn + b * 16 + lo, acc[a][b][q] * wt);
            }
        }
    }
}

// ---------------- host ----------------
extern "C" void kernel_launch(void* const* d_in, const int* in_sizes, int n_in,
                              void* d_out, int out_size, void* d_ws, size_t ws_size,
                              hipStream_t stream)
{
    const float* x   = (const float*)d_in[0];
    const float* gw  = (const float*)d_in[1];
    const float* w1s = (const float*)d_in[2];
    const float* w3s = (const float*)d_in[3];
    const float* w2s = (const float*)d_in[4];
    float* out = (float*)d_out;
    char* ws = (char*)d_ws;

    int*   counts  = (int*)(ws + 0);
    int*   bases   = (int*)(ws + 128);
    int*   sel0    = (int*)(ws + 1024);
    int*   sel1    = (int*)(ws + 1024 + 4 * T_TOK);
    float* w0f     = (float*)(ws + 1024 + 8 * T_TOK);
    float* w1f     = (float*)(ws + 1024 + 12 * T_TOK);
    int*   pairTok = (int*)(ws + 1024 + 16 * T_TOK);
    float* pairW   = (float*)(ws + 1024 + 16 * T_TOK + 4 * NPAIR);

    const int cands[8] = {1, 2, 4, 7, 8, 14, 28, 56};
    int NC = 56;
    for (int ci = 0; ci < 8; ++ci) {
        int nc = cands[ci];
        int NBc = 56 / nc, Fcc = FFN / nc, KT2c = Fcc / 32;
        size_t sz13 = (size_t)NEXP * NBc * KT1 * SLAB;
        size_t sz2  = (size_t)NEXP * 16 * KT2c * SLAB;
        size_t sxp  = (size_t)(NPAIR + BM) * HID * 2;
        size_t shb  = (size_t)(NPAIR + BM) * Fcc * 2;
        if (262144 + 2 * sz13 + sz2 + sxp + shb <= ws_size) { NC = nc; break; }
    }
    int NBc = 56 / NC, Fc = FFN / NC, KT2c = Fc / 32;
    size_t sz13 = (size_t)NEXP * NBc * KT1 * SLAB;
    size_t sz2  = (size_t)NEXP * 16 * KT2c * SLAB;
    size_t sxp  = (size_t)(NPAIR + BM) * HID * 2;
    short* w1r   = (short*)(ws + 262144);
    short* w3r   = (short*)(ws + 262144 + sz13);
    short* w2r   = (short*)(ws + 262144 + 2 * sz13);
    short* xperm = (short*)(ws + 262144 + 2 * sz13 + sz2);
    short* hbuf  = (short*)(ws + 262144 + 2 * sz13 + sz2 + sxp);

    hipMemsetAsync(ws, 0, 1024, stream);
    hipMemsetAsync(d_out, 0, (size_t)out_size * sizeof(float), stream);
    moe_router<<<T_TOK / 4, 256, 0, stream>>>(x, gw, counts, sel0, sel1, w0f, w1f);
    moe_bases<<<1, 64, 0, stream>>>(counts, bases);
    moe_scatter<<<NEXP, 256, 0, stream>>>(sel0, sel1, w0f, w1f, bases, pairTok, pairW);
    moe_xperm<<<NPAIR / 4, 256, 0, stream>>>(x, pairTok, xperm);

    for (int c = 0; c < NC; ++c) {
        moe_retile<<<NEXP * NBc * KT1, 256, 0, stream>>>(
            w1s + (size_t)c * Fc, (size_t)HID * FFN, FFN, w1r, NBc, KT1);
        moe_retile<<<NEXP * NBc * KT1, 256, 0, stream>>>(
            w3s + (size_t)c * Fc, (size_t)HID * FFN, FFN, w3r, NBc, KT1);
        moe_retile<<<NEXP * 16 * KT2c, 256, 0, stream>>>(
            w2s + (size_t)(c * Fc) * HID, (size_t)FFN * HID, HID, w2r, 16, KT2c);
        moe_g1<<<NEXP * NBc * MT, 256, 0, stream>>>(
            xperm, w1r, w3r, counts, bases, hbuf, NBc, Fc);
        moe_g2<<<NEXP * 16 * MT, 256, 0, stream>>>(
            hbuf, w2r, counts, bases, pairTok, pairW, out, Fc, KT2c);
    }
    (void)in_sizes; (void)n_in;
}

// Round 6
// 1836.114 us; speedup vs baseline: 2.1283x; 2.1283x over previous
//
#include <hip/hip_runtime.h>
#include <hip/hip_bf16.h>

#define T_TOK 4096
#define HID   2048
#define FFN   7168
#define NEXP  8
#define BM    128
#define BN    128
#define MT    16
#define NPAIR (T_TOK * 2)
#define KT1   (HID / 32)   // 64 k-slabs for GEMM1
#define SLAB  8192         // bytes per [128n][32k] bf16 slab

typedef __attribute__((ext_vector_type(8))) short bf16x8;
typedef __attribute__((ext_vector_type(4))) short bf16x4;
typedef __attribute__((ext_vector_type(4))) float f32x4;

union F4 { float4 v; float f[4]; };

__device__ __forceinline__ short f2bfs(float f) {
    unsigned u = __float_as_uint(f);
    return (short)((u + 0x7FFFu + ((u >> 16) & 1u)) >> 16);
}
// slot swizzle for 64B rows (4x 16B slots): slot holding k-group g of row n is g ^ swzi(n)
__device__ __forceinline__ int swzi(int n) { return (n ^ (n >> 2)) & 3; }

__device__ __forceinline__ void gl16(const void* g, void* l) {
    __builtin_amdgcn_global_load_lds(
        (const __attribute__((address_space(1))) unsigned int*)g,
        (__attribute__((address_space(3))) unsigned int*)l, 16, 0, 0);
}

// ---------------- Router ----------------
__global__ __launch_bounds__(256) void moe_router(
    const float* __restrict__ x, const float* __restrict__ gw,
    int* __restrict__ counts, int* __restrict__ sel0, int* __restrict__ sel1,
    float* __restrict__ w0o, float* __restrict__ w1o)
{
    int wave = threadIdx.x >> 6, lane = threadIdx.x & 63;
    int t = blockIdx.x * 4 + wave;
    const float* xr = x + (size_t)t * HID;
    float acc[NEXP];
#pragma unroll
    for (int e = 0; e < NEXP; ++e) acc[e] = 0.f;
    for (int i = 0; i < HID / 64; ++i) {
        int k = lane + i * 64;
        float xv = xr[k];
        const float4* g = reinterpret_cast<const float4*>(gw + (size_t)k * NEXP);
        float4 g0 = g[0], g1 = g[1];
        acc[0] += xv * g0.x; acc[1] += xv * g0.y; acc[2] += xv * g0.z; acc[3] += xv * g0.w;
        acc[4] += xv * g1.x; acc[5] += xv * g1.y; acc[6] += xv * g1.z; acc[7] += xv * g1.w;
    }
#pragma unroll
    for (int e = 0; e < NEXP; ++e) {
        float v = acc[e];
#pragma unroll
        for (int s = 32; s > 0; s >>= 1) v += __shfl_xor(v, s);
        acc[e] = v;
    }
    if (lane == 0) {
        float mx = acc[0];
        for (int e = 1; e < NEXP; ++e) mx = fmaxf(mx, acc[e]);
        float p[NEXP];
        for (int e = 0; e < NEXP; ++e) p[e] = __expf(acc[e] - mx);
        int e0 = 0;
        for (int e = 1; e < NEXP; ++e) if (p[e] > p[e0]) e0 = e;
        int e1 = (e0 == 0) ? 1 : 0;
        for (int e = 0; e < NEXP; ++e) if (e != e0 && p[e] > p[e1]) e1 = e;
        float rs = p[e0] + p[e1];
        sel0[t] = e0; sel1[t] = e1;
        w0o[t] = p[e0] / rs; w1o[t] = p[e1] / rs;
        atomicAdd(&counts[e0], 1); atomicAdd(&counts[e1], 1);
    }
}

__global__ void moe_bases(const int* __restrict__ counts, int* __restrict__ bases)
{
    if (threadIdx.x == 0 && blockIdx.x == 0) {
        int b = 0;
        for (int e = 0; e < NEXP; ++e) { bases[e] = b; b += counts[e]; }
    }
}

// ---------------- Deterministic scatter ----------------
__global__ __launch_bounds__(256) void moe_scatter(
    const int* __restrict__ sel0, const int* __restrict__ sel1,
    const float* __restrict__ w0, const float* __restrict__ w1,
    const int* __restrict__ bases, int* __restrict__ pairTok, float* __restrict__ pairW)
{
    int e = blockIdx.x;
    __shared__ int wsum[4];
    __shared__ int runningS;
    int tid = threadIdx.x, wave = tid >> 6, lane = tid & 63;
    if (tid == 0) runningS = bases[e];
    __syncthreads();
    for (int i0 = 0; i0 < T_TOK; i0 += 256) {
        int t = i0 + tid;
        bool f0 = (sel0[t] == e), f1 = (sel1[t] == e);
        bool sel = f0 || f1;
        unsigned long long mm = __ballot(sel);
        if (lane == 0) wsum[wave] = __popcll(mm);
        __syncthreads();
        int woff = 0;
#pragma unroll
        for (int w = 0; w < 4; ++w) if (w < wave) woff += wsum[w];
        int tot = wsum[0] + wsum[1] + wsum[2] + wsum[3];
        int pre = __popcll(mm & ((1ull << lane) - 1ull));
        if (sel) {
            int pos = runningS + woff + pre;
            pairTok[pos] = t;
            pairW[pos] = f0 ? w0[t] : w1[t];
        }
        __syncthreads();
        if (tid == 0) runningS += tot;
        __syncthreads();
    }
}

// ---------------- xperm: gather routed token rows as bf16 ----------------
__global__ __launch_bounds__(256) void moe_xperm(
    const float* __restrict__ x, const int* __restrict__ pairTok,
    short* __restrict__ xperm)
{
    int p = blockIdx.x * 4 + (threadIdx.x >> 6);
    int lane = threadIdx.x & 63;
    const float* s = x + (size_t)pairTok[p] * HID;
    short* d = xperm + (size_t)p * HID;
#pragma unroll
    for (int i = 0; i < HID / 512; ++i) {
        int k = (i * 64 + lane) * 8;
        float4 f0 = *reinterpret_cast<const float4*>(s + k);
        float4 f1 = *reinterpret_cast<const float4*>(s + k + 4);
        union { bf16x8 v; short sh[8]; } u;
        u.sh[0] = f2bfs(f0.x); u.sh[1] = f2bfs(f0.y); u.sh[2] = f2bfs(f0.z); u.sh[3] = f2bfs(f0.w);
        u.sh[4] = f2bfs(f1.x); u.sh[5] = f2bfs(f1.y); u.sh[6] = f2bfs(f1.z); u.sh[7] = f2bfs(f1.w);
        *reinterpret_cast<bf16x8*>(d + k) = u.v;
    }
}

// ---------------- retile: fp32 [K][N] -> bf16 swizzled 8KB slabs [n:128][k:32] ----------------
// slab L = (e*NB + nb)*KT + kt; byte(n,k) = n*64 + ((k>>3 ^ swzi(n))*16) + (k&7)*2
__global__ __launch_bounds__(256) void moe_retile(
    const float* __restrict__ src, size_t eStride, int rowStride,
    short* __restrict__ dst, int NB, int KT)
{
    int L = blockIdx.x;
    int e = L / (NB * KT);
    int r = L - e * (NB * KT);
    int nb = r / KT, kt = r - nb * KT;
    const float* s0 = src + (size_t)e * eStride + (size_t)(kt * 32) * rowStride + nb * 128;
    __shared__ __align__(16) short S[4096];
    int t = threadIdx.x;
    int kq = t >> 5, nq = t & 31;            // 4x4 unit at k=kq*4, n=nq*4
    const float* p = s0 + (size_t)(kq * 4) * rowStride + nq * 4;
    F4 r0, r1, r2, r3;
    r0.v = *reinterpret_cast<const float4*>(p);
    r1.v = *reinterpret_cast<const float4*>(p + rowStride);
    r2.v = *reinterpret_cast<const float4*>(p + 2 * (size_t)rowStride);
    r3.v = *reinterpret_cast<const float4*>(p + 3 * (size_t)rowStride);
#pragma unroll
    for (int c = 0; c < 4; ++c) {
        int n = nq * 4 + c;
        bf16x4 v = { f2bfs(r0.f[c]), f2bfs(r1.f[c]), f2bfs(r2.f[c]), f2bfs(r3.f[c]) };
        unsigned byte = (unsigned)(n * 64 + (((kq >> 1) ^ swzi(n)) * 16) + (kq & 1) * 8);
        *reinterpret_cast<bf16x4*>(reinterpret_cast<char*>(S) + byte) = v;
    }
    __syncthreads();
    char* d = reinterpret_cast<char*>(dst) + (size_t)L * SLAB;
    const char* sc = reinterpret_cast<const char*>(S);
    *reinterpret_cast<bf16x8*>(d + t * 16) = *reinterpret_cast<const bf16x8*>(sc + t * 16);
    *reinterpret_cast<bf16x8*>(d + t * 16 + 4096) = *reinterpret_cast<const bf16x8*>(sc + t * 16 + 4096);
}

// ---------------- GEMM1: h = silu(x@W1)*(x@W3), 2-phase dbuf pipeline ----------------
// NOTE launch_bounds(256,2): unified VGPR+AGPR cap = 256/thread. acc1+acc3 alone
// are 128 regs; declaring 3 waves/EU (cap ~170) spills accumulators to scratch
// (round 5: WRITE_SIZE 6 GB, 4x slowdown). Do not raise.
__global__ __launch_bounds__(256, 2) void moe_g1(
    const short* __restrict__ xperm, const short* __restrict__ w1r, const short* __restrict__ w3r,
    const int* __restrict__ counts, const int* __restrict__ bases,
    short* __restrict__ hbuf, int NBc, int Fc)
{
    int L = blockIdx.x;
    int e = L & 7;                        // expert <-> XCD binding
    int i = L >> 3;
    int nb = i / MT, m = i - nb * MT;
    int cnt = counts[e];
    int m0 = m * BM;
    if (m0 >= cnt) return;
    int base = bases[e];
    int rows = cnt - m0; if (rows > BM) rows = BM;

    __shared__ __align__(16) short As[2][4096], B1s[2][4096], B3s[2][4096];

    int tid = threadIdx.x, lane = tid & 63, w = tid >> 6;
    int wm = (w >> 1) * 64, wn = (w & 1) * 64;

    // A per-lane swizzle-baked sources (wave w stages rows [w*32, w*32+32))
    const char* aS[2];
#pragma unroll
    for (int j = 0; j < 2; ++j) {
        int row = w * 32 + j * 16 + (lane >> 2);
        aS[j] = reinterpret_cast<const char*>(xperm) +
                (size_t)(base + m0 + row) * (HID * 2) +
                (unsigned)(((lane & 3) ^ swzi(row)) * 16);
    }
    size_t slabBase = (size_t)((e * NBc + nb) * KT1) * SLAB;
    const char* b1S = reinterpret_cast<const char*>(w1r) + slabBase + w * 2048 + lane * 16;
    const char* b3S = reinterpret_cast<const char*>(w3r) + slabBase + w * 2048 + lane * 16;

    f32x4 acc1[4][4], acc3[4][4];
#pragma unroll
    for (int a = 0; a < 4; ++a)
#pragma unroll
        for (int b = 0; b < 4; ++b) { acc1[a][b] = (f32x4){0.f,0.f,0.f,0.f}; acc3[a][b] = (f32x4){0.f,0.f,0.f,0.f}; }

    // loop-invariant fragment read offsets (BK=32: one k-group per lane)
    unsigned aRB[4], bRB[4];
    int gq = lane >> 4;
#pragma unroll
    for (int a = 0; a < 4; ++a) {
        int rA = wm + a * 16 + (lane & 15);
        aRB[a] = (unsigned)(rA * 64 + ((gq ^ swzi(rA)) * 16));
        int rB = wn + a * 16 + (lane & 15);
        bRB[a] = (unsigned)(rB * 64 + ((gq ^ swzi(rB)) * 16));
    }

#define G1_STAGE(B, KT_IDX) do { \
    int _kt = (KT_IDX); \
    gl16(aS[0] + (size_t)_kt * 64, (char*)As[B] + w * 2048); \
    gl16(aS[1] + (size_t)_kt * 64, (char*)As[B] + w * 2048 + 1024); \
    gl16(b1S + (size_t)_kt * SLAB, (char*)B1s[B] + w * 2048); \
    gl16(b1S + (size_t)_kt * SLAB + 1024, (char*)B1s[B] + w * 2048 + 1024); \
    gl16(b3S + (size_t)_kt * SLAB, (char*)B3s[B] + w * 2048); \
    gl16(b3S + (size_t)_kt * SLAB + 1024, (char*)B3s[B] + w * 2048 + 1024); \
} while (0)

#define G1_COMPUTE(B) do { \
    bf16x8 af[4], b1f[4], b3f[4]; \
    _Pragma("unroll") \
    for (int a = 0; a < 4; ++a) \
        af[a] = *reinterpret_cast<const bf16x8*>((const char*)As[B] + aRB[a]); \
    _Pragma("unroll") \
    for (int b = 0; b < 4; ++b) { \
        b1f[b] = *reinterpret_cast<const bf16x8*>((const char*)B1s[B] + bRB[b]); \
        b3f[b] = *reinterpret_cast<const bf16x8*>((const char*)B3s[B] + bRB[b]); \
    } \
    _Pragma("unroll") \
    for (int a = 0; a < 4; ++a) \
        _Pragma("unroll") \
        for (int b = 0; b < 4; ++b) { \
            acc1[a][b] = __builtin_amdgcn_mfma_f32_16x16x32_bf16(af[a], b1f[b], acc1[a][b], 0, 0, 0); \
            acc3[a][b] = __builtin_amdgcn_mfma_f32_16x16x32_bf16(af[a], b3f[b], acc3[a][b], 0, 0, 0); \
        } \
} while (0)

    G1_STAGE(0, 0);
    __syncthreads();
#pragma unroll 1
    for (int kt = 0; kt < KT1; kt += 2) {
        G1_STAGE(1, kt + 1);       // issue next-tile loads BEFORE compute
        G1_COMPUTE(0);
        __syncthreads();           // drains buf1 staging, releases buf0
        if (kt + 2 < KT1) G1_STAGE(0, kt + 2);
        G1_COMPUTE(1);
        __syncthreads();
    }

    int hi = lane >> 4, lo = lane & 15;
#pragma unroll
    for (int a = 0; a < 4; ++a) {
#pragma unroll
        for (int q = 0; q < 4; ++q) {
            int rowL = wm + a * 16 + hi * 4 + q;
            if (rowL < rows) {
                short* dst = hbuf + (size_t)(base + m0 + rowL) * Fc + nb * 128;
#pragma unroll
                for (int b = 0; b < 4; ++b) {
                    float z = acc1[a][b][q];
                    float hv = (z / (1.f + __expf(-z))) * acc3[a][b][q];
                    dst[wn + b * 16 + lo] = f2bfs(hv);
                }
            }
        }
    }
}

// ---------------- GEMM2: out[tok] += w * (h @ W2), 2-phase dbuf ----------------
__global__ __launch_bounds__(256, 2) void moe_g2(
    const short* __restrict__ hbuf, const short* __restrict__ w2r,
    const int* __restrict__ counts, const int* __restrict__ bases,
    const int* __restrict__ pairTok, const float* __restrict__ pairW,
    float* __restrict__ out, int Fc, int KT2)
{
    const int NB2 = HID / BN;             // 16
    int L = blockIdx.x;
    int e = L & 7;
    int i = L >> 3;
    int nb = i / MT, m = i - nb * MT;
    int cnt = counts[e];
    int m0 = m * BM;
    if (m0 >= cnt) return;
    int base = bases[e];
    int rows = cnt - m0; if (rows > BM) rows = BM;

    __shared__ __align__(16) short As[2][4096], Bs[2][4096];
    __shared__ int tokS[BM];
    __shared__ float wS[BM];

    int tid = threadIdx.x, lane = tid & 63, w = tid >> 6;
    if (tid < BM) {
        tokS[tid] = (tid < rows) ? pairTok[base + m0 + tid] : 0;
        wS[tid]   = (tid < rows) ? pairW[base + m0 + tid] : 0.f;
    }
    int wm = (w >> 1) * 64, wn = (w & 1) * 64;

    const char* aS[2];
#pragma unroll
    for (int j = 0; j < 2; ++j) {
        int row = w * 32 + j * 16 + (lane >> 2);
        aS[j] = reinterpret_cast<const char*>(hbuf) +
                (size_t)(base + m0 + row) * (size_t)(Fc * 2) +
                (unsigned)(((lane & 3) ^ swzi(row)) * 16);
    }
    size_t slabBase = (size_t)((e * NB2 + nb) * KT2) * SLAB;
    const char* bS = reinterpret_cast<const char*>(w2r) + slabBase + w * 2048 + lane * 16;

    f32x4 acc[4][4];
#pragma unroll
    for (int a = 0; a < 4; ++a)
#pragma unroll
        for (int b = 0; b < 4; ++b) acc[a][b] = (f32x4){0.f,0.f,0.f,0.f};

    unsigned aRB[4], bRB[4];
    int gq = lane >> 4;
#pragma unroll
    for (int a = 0; a < 4; ++a) {
        int rA = wm + a * 16 + (lane & 15);
        aRB[a] = (unsigned)(rA * 64 + ((gq ^ swzi(rA)) * 16));
        int rB = wn + a * 16 + (lane & 15);
        bRB[a] = (unsigned)(rB * 64 + ((gq ^ swzi(rB)) * 16));
    }

#define G2_STAGE(B, KT_IDX) do { \
    int _kt = (KT_IDX); \
    gl16(aS[0] + (size_t)_kt * 64, (char*)As[B] + w * 2048); \
    gl16(aS[1] + (size_t)_kt * 64, (char*)As[B] + w * 2048 + 1024); \
    gl16(bS + (size_t)_kt * SLAB, (char*)Bs[B] + w * 2048); \
    gl16(bS + (size_t)_kt * SLAB + 1024, (char*)Bs[B] + w * 2048 + 1024); \
} while (0)

#define G2_COMPUTE(B) do { \
    bf16x8 af[4], bfr[4]; \
    _Pragma("unroll") \
    for (int a = 0; a < 4; ++a) \
        af[a] = *reinterpret_cast<const bf16x8*>((const char*)As[B] + aRB[a]); \
    _Pragma("unroll") \
    for (int b = 0; b < 4; ++b) \
        bfr[b] = *reinterpret_cast<const bf16x8*>((const char*)Bs[B] + bRB[b]); \
    _Pragma("unroll") \
    for (int a = 0; a < 4; ++a) \
        _Pragma("unroll") \
        for (int b = 0; b < 4; ++b) \
            acc[a][b] = __builtin_amdgcn_mfma_f32_16x16x32_bf16(af[a], bfr[b], acc[a][b], 0, 0, 0); \
} while (0)

    __syncthreads();                      // tokS/wS visible
    G2_STAGE(0, 0);
    __syncthreads();
#pragma unroll 1
    for (int kt = 0; kt < KT2; kt += 2) {
        G2_STAGE(1, kt + 1);
        G2_COMPUTE(0);
        __syncthreads();
        if (kt + 2 < KT2) G2_STAGE(0, kt + 2);
        G2_COMPUTE(1);
        __syncthreads();
    }

    int hi = lane >> 4, lo = lane & 15;
#pragma unroll
    for (int a = 0; a < 4; ++a) {
#pragma unroll
        for (int q = 0; q < 4; ++q) {
            int rowL = wm + a * 16 + hi * 4 + q;
            if (rowL < rows) {
                float wt = wS[rowL];
                float* dst = out + (size_t)tokS[rowL] * HID + nb * 128;
#pragma unroll
                for (int b = 0; b < 4; ++b)
                    atomicAdd(dst + wn + b * 16 + lo, acc[a][b][q] * wt);
            }
        }
    }
}

// ---------------- host ----------------
extern "C" void kernel_launch(void* const* d_in, const int* in_sizes, int n_in,
                              void* d_out, int out_size, void* d_ws, size_t ws_size,
                              hipStream_t stream)
{
    const float* x   = (const float*)d_in[0];
    const float* gw  = (const float*)d_in[1];
    const float* w1s = (const float*)d_in[2];
    const float* w3s = (const float*)d_in[3];
    const float* w2s = (const float*)d_in[4];
    float* out = (float*)d_out;
    char* ws = (char*)d_ws;

    int*   counts  = (int*)(ws + 0);
    int*   bases   = (int*)(ws + 128);
    int*   sel0    = (int*)(ws + 1024);
    int*   sel1    = (int*)(ws + 1024 + 4 * T_TOK);
    float* w0f     = (float*)(ws + 1024 + 8 * T_TOK);
    float* w1f     = (float*)(ws + 1024 + 12 * T_TOK);
    int*   pairTok = (int*)(ws + 1024 + 16 * T_TOK);
    float* pairW   = (float*)(ws + 1024 + 16 * T_TOK + 4 * NPAIR);

    const int cands[8] = {1, 2, 4, 7, 8, 14, 28, 56};
    int NC = 56;
    for (int ci = 0; ci < 8; ++ci) {
        int nc = cands[ci];
        int NBc = 56 / nc, Fcc = FFN / nc, KT2c = Fcc / 32;
        size_t sz13 = (size_t)NEXP * NBc * KT1 * SLAB;
        size_t sz2  = (size_t)NEXP * 16 * KT2c * SLAB;
        size_t sxp  = (size_t)(NPAIR + BM) * HID * 2;
        size_t shb  = (size_t)(NPAIR + BM) * Fcc * 2;
        if (262144 + 2 * sz13 + sz2 + sxp + shb <= ws_size) { NC = nc; break; }
    }
    int NBc = 56 / NC, Fc = FFN / NC, KT2c = Fc / 32;
    size_t sz13 = (size_t)NEXP * NBc * KT1 * SLAB;
    size_t sz2  = (size_t)NEXP * 16 * KT2c * SLAB;
    size_t sxp  = (size_t)(NPAIR + BM) * HID * 2;
    short* w1r   = (short*)(ws + 262144);
    short* w3r   = (short*)(ws + 262144 + sz13);
    short* w2r   = (short*)(ws + 262144 + 2 * sz13);
    short* xperm = (short*)(ws + 262144 + 2 * sz13 + sz2);
    short* hbuf  = (short*)(ws + 262144 + 2 * sz13 + sz2 + sxp);

    hipMemsetAsync(ws, 0, 1024, stream);
    hipMemsetAsync(d_out, 0, (size_t)out_size * sizeof(float), stream);
    moe_router<<<T_TOK / 4, 256, 0, stream>>>(x, gw, counts, sel0, sel1, w0f, w1f);
    moe_bases<<<1, 64, 0, stream>>>(counts, bases);
    moe_scatter<<<NEXP, 256, 0, stream>>>(sel0, sel1, w0f, w1f, bases, pairTok, pairW);
    moe_xperm<<<NPAIR / 4, 256, 0, stream>>>(x, pairTok, xperm);

    for (int c = 0; c < NC; ++c) {
        moe_retile<<<NEXP * NBc * KT1, 256, 0, stream>>>(
            w1s + (size_t)c * Fc, (size_t)HID * FFN, FFN, w1r, NBc, KT1);
        moe_retile<<<NEXP * NBc * KT1, 256, 0, stream>>>(
            w3s + (size_t)c * Fc, (size_t)HID * FFN, FFN, w3r, NBc, KT1);
        moe_retile<<<NEXP * 16 * KT2c, 256, 0, stream>>>(
            w2s + (size_t)(c * Fc) * HID, (size_t)FFN * HID, HID, w2r, 16, KT2c);
        moe_g1<<<NEXP * NBc * MT, 256, 0, stream>>>(
            xperm, w1r, w3r, counts, bases, hbuf, NBc, Fc);
        moe_g2<<<NEXP * 16 * MT, 256, 0, stream>>>(
            hbuf, w2r, counts, bases, pairTok, pairW, out, Fc, KT2c);
    }
    (void)in_sizes; (void)n_in;
}